// Round 12
// baseline (226.990 us; speedup 1.0000x reference)
//
#include <hip/hip_runtime.h>
#include <cstdint>
#include <cstddef>

#define MTOT 16384      // B*S
#define MPAD 16388      // + 4 zero pad rows
#define INCH 512        // W*E
#define NF   256        // filters per conv
#define PREPB 6144      // prep blocks (2048 per conv)

typedef __attribute__((ext_vector_type(4))) float f32x4;
typedef __attribute__((ext_vector_type(8))) short bf16x8;

__device__ __forceinline__ short f2bf(float f) {
    union { float f; unsigned u; } v; v.f = f;
    unsigned r = v.u + 0x7FFFu + ((v.u >> 16) & 1u);
    return (short)(r >> 16);
}

__device__ __forceinline__ void gld16(const short* g, short* l) {
    __builtin_amdgcn_global_load_lds(
        (const __attribute__((address_space(1))) unsigned int*)g,
        (__attribute__((address_space(3))) unsigned int*)l,
        16, 0, 0);
}

// ---------------- 1. fused: conv-weight prep + embedding gather -------------
// MEASUREMENT: reps=4 (idempotent). Reps 2-4 are L3-fed for x -> per-rep
// deltas + hbm_gbps + VALUBusy diagnose BW-bound vs scan-bound.
__global__ void embed_prep(const float* __restrict__ x, const float* __restrict__ ew,
                           short* __restrict__ emb,
                           const float* __restrict__ w0, const float* __restrict__ w1,
                           const float* __restrict__ w2, short* __restrict__ Wtb,
                           int reps) {
    int tid = threadIdx.x;
#pragma clang loop unroll(disable)
    for (int rep = 0; rep < reps; ++rep) {
    if (blockIdx.x < PREPB) {
        int blk = blockIdx.x;
        int conv = blk >> 11;
        int ki = conv + 2;
        int K = 512 * ki;
        int idx = (blk & 2047) * 256 + tid;
        if (idx >= K * NF) continue;
        int u = idx >> 9;
        int ic = idx & 511;
        int f = u / ki;
        int j = u - f * ki;
        const float* w = (conv == 0) ? w0 : (conv == 1) ? w1 : w2;
        float val = w[(size_t)f * K + ic * ki + j];
        int k = j * 512 + ic;
        int kt = k >> 6, kl = k & 63;
        int kc = kl >> 3, klo = kl & 7;
        int nb = f >> 7, fr = f & 127;
        int cc = kc ^ (fr & 7);
        size_t off = (conv == 0) ? 0 : (conv == 1) ? 262144 : 655360;
        Wtb[off + (((size_t)(kt * 2 + nb) * 128 + fr) * 8 + cc) * 8 + klo] = f2bf(val);
        continue;
    }
    int m = blockIdx.x - PREPB;
    if (m >= MTOT) {
        if (tid < 64) {
            uint4 z = make_uint4(0u, 0u, 0u, 0u);
            *(uint4*)&emb[(size_t)m * INCH + tid * 8] = z;
        }
        continue;
    }
    int w = tid >> 4, u = tid & 15;
    const float* xr = x + ((size_t)m * 16 + w) * 128 + u * 8;
    float4 a0 = *(const float4*)xr;
    float4 a1 = *(const float4*)(xr + 4);
    float vals[8] = {a0.x, a0.y, a0.z, a0.w, a1.x, a1.y, a1.z, a1.w};
    int myidx = 0;
#pragma unroll
    for (int jj = 0; jj < 8; ++jj)
        if (vals[jj] != 0.f) myidx = u * 8 + jj;
#pragma unroll
    for (int off = 1; off < 16; off <<= 1)
        myidx = max(myidx, __shfl_xor(myidx, off));
    if (u < 4) {
        const float* er = ew + (size_t)myidx * 32 + u * 8;
        float4 e0 = *(const float4*)er;
        float4 e1 = *(const float4*)(er + 4);
        short h[8];
        h[0] = f2bf(e0.x); h[1] = f2bf(e0.y); h[2] = f2bf(e0.z); h[3] = f2bf(e0.w);
        h[4] = f2bf(e1.x); h[5] = f2bf(e1.y); h[6] = f2bf(e1.z); h[7] = f2bf(e1.w);
        *(uint4*)&emb[(size_t)m * INCH + w * 32 + u * 8] = *(uint4*)h;
    }
    }
}

// ---------------- 2. conv GEMM (R11 structure, reps=3) ----------------------
__launch_bounds__(256)
__global__ void conv_gemm(const short* __restrict__ emb, const short* __restrict__ Wtb,
                          const float* __restrict__ cb0, const float* __restrict__ cb1,
                          const float* __restrict__ cb2,
                          float* __restrict__ sumP, float* __restrict__ ssqP,
                          float* __restrict__ mxF, float* __restrict__ mnF,
                          int reps) {
    int o = blockIdx.x;
    int logical = (o & 7) * 96 + (o >> 3);
    int mb = logical / 6;
    int r6 = logical - mb * 6;
    int conv = r6 >> 1;
    int nb = r6 & 1;
    int ki = conv + 2;
    int m0 = mb * 128;
    const short* Wc = Wtb + ((conv == 0) ? 0 : (conv == 1) ? 262144 : 655360);

    __shared__ __align__(16) short As[128 * 64];
    __shared__ __align__(16) short Bs[128 * 64];

    int tid = threadIdx.x;
    int wv = tid >> 6, lane = tid & 63, g = lane >> 4, ln = lane & 15;
    int wr = wv >> 1, wc = wv & 1;

    int arow[4], acol[4];
#pragma unroll
    for (int q = 0; q < 4; ++q) {
        int c = q * 256 + tid;
        arow[q] = c >> 3;
        acol[q] = ((c & 7) ^ (arow[q] & 7)) * 8;
    }
    int aOff[2][4], bOff[2][4];
#pragma unroll
    for (int kk = 0; kk < 2; ++kk)
#pragma unroll
        for (int i = 0; i < 4; ++i) {
            int R = wr * 64 + i * 16 + ln;
            aOff[kk][i] = R * 64 + (((kk * 4 + g) ^ (R & 7)) * 8);
            int F = wc * 64 + i * 16 + ln;
            bOff[kk][i] = F * 64 + (((kk * 4 + g) ^ (F & 7)) * 8);
        }

#pragma clang loop unroll(disable)
    for (int rep = 0; rep < reps; ++rep) {
    f32x4 acc[4][4];
#pragma unroll
    for (int i = 0; i < 4; ++i)
#pragma unroll
        for (int n = 0; n < 4; ++n) acc[i][n] = (f32x4){0.f, 0.f, 0.f, 0.f};

    for (int j = 0; j < ki; ++j) {
        const short* embj = emb + (size_t)(m0 + j) * INCH;
        for (int ic0 = 0; ic0 < INCH; ic0 += 64) {
            int kt = j * 8 + (ic0 >> 6);
            const short* Bsrc = Wc + (size_t)(kt * 2 + nb) * 8192;
            __syncthreads();
#pragma unroll
            for (int q = 0; q < 4; ++q) {
                gld16(embj + (size_t)arow[q] * INCH + ic0 + acol[q],
                      As + q * 2048 + wv * 512);
                gld16(Bsrc + (q * 256 + tid) * 8,
                      Bs + q * 2048 + wv * 512);
            }
            __syncthreads();
#pragma unroll
            for (int kk = 0; kk < 2; ++kk) {
                bf16x8 afr[4], bfr[4];
#pragma unroll
                for (int mi = 0; mi < 4; ++mi) afr[mi] = *(const bf16x8*)&As[aOff[kk][mi]];
#pragma unroll
                for (int ni = 0; ni < 4; ++ni) bfr[ni] = *(const bf16x8*)&Bs[bOff[kk][ni]];
#pragma unroll
                for (int mi = 0; mi < 4; ++mi)
#pragma unroll
                    for (int ni = 0; ni < 4; ++ni)
                        acc[mi][ni] = __builtin_amdgcn_mfma_f32_16x16x32_bf16(afr[mi], bfr[ni], acc[mi][ni], 0, 0, 0);
            }
        }
    }

    int L = 127 - conv;
    const float* cbp = (conv == 0) ? cb0 : (conv == 1) ? cb1 : cb2;
    float s[4] = {0.f, 0.f, 0.f, 0.f}, q[4] = {0.f, 0.f, 0.f, 0.f};
    float mx[4], mn[4], cb[4];
#pragma unroll
    for (int ni = 0; ni < 4; ++ni) {
        mx[ni] = -3.0e38f; mn[ni] = 3.0e38f;
        cb[ni] = cbp[nb * 128 + wc * 64 + ni * 16 + ln];
    }
#pragma unroll
    for (int mi = 0; mi < 4; ++mi) {
#pragma unroll
        for (int r = 0; r < 4; ++r) {
            int t = wr * 64 + mi * 16 + g * 4 + r;
            if (t >= L) continue;
#pragma unroll
            for (int ni = 0; ni < 4; ++ni) {
                float c = acc[mi][ni][r] + cb[ni];
                s[ni] += c; q[ni] += c * c;
                mx[ni] = fmaxf(mx[ni], c); mn[ni] = fminf(mn[ni], c);
            }
        }
    }
#pragma unroll
    for (int off = 16; off < 64; off <<= 1) {
#pragma unroll
        for (int ni = 0; ni < 4; ++ni) {
            s[ni] += __shfl_xor(s[ni], off);
            q[ni] += __shfl_xor(q[ni], off);
            mx[ni] = fmaxf(mx[ni], __shfl_xor(mx[ni], off));
            mn[ni] = fminf(mn[ni], __shfl_xor(mn[ni], off));
        }
    }
    __syncthreads();
    float* sm = (float*)As;
    if (g == 0) {
#pragma unroll
        for (int ni = 0; ni < 4; ++ni) {
            int col = wc * 64 + ni * 16 + ln;
            int oo = wr * 128 + col;
            sm[oo] = s[ni]; sm[256 + oo] = q[ni];
            sm[512 + oo] = mx[ni]; sm[768 + oo] = mn[ni];
        }
    }
    __syncthreads();
    if (tid < 128) {
        float S  = sm[tid] + sm[128 + tid];
        float Q  = sm[256 + tid] + sm[384 + tid];
        float MX = fmaxf(sm[512 + tid], sm[640 + tid]);
        float MN = fminf(sm[768 + tid], sm[896 + tid]);
        size_t off2 = ((size_t)(conv * 128 + mb)) * 256 + nb * 128 + tid;
        sumP[off2] = S; ssqP[off2] = Q; mxF[off2] = MX; mnF[off2] = MN;
    }
    __syncthreads();   // rep boundary
    }
}

// ---------------- 3. BN stats only: af/df[768] (3 blocks x 1024) ------------
__global__ void bn_stats(const float* __restrict__ sumP, const float* __restrict__ ssqP,
                         const float* __restrict__ g0, const float* __restrict__ g1,
                         const float* __restrict__ g2,
                         const float* __restrict__ b0, const float* __restrict__ b1,
                         const float* __restrict__ b2,
                         float* __restrict__ af, float* __restrict__ df) {
    int conv = blockIdx.x;
    int tid = threadIdx.x;
    int part = tid >> 8, f = tid & 255;
    float s = 0.f, q = 0.f;
#pragma unroll 4
    for (int mb = part * 32; mb < part * 32 + 32; ++mb) {
        size_t o = ((size_t)(conv * 128 + mb)) * 256 + f;
        s += sumP[o]; q += ssqP[o];
    }
    __shared__ float sred[4][256], qred[4][256];
    sred[part][f] = s; qred[part][f] = q;
    __syncthreads();
    if (part == 0) {
        s = sred[0][f] + sred[1][f] + sred[2][f] + sred[3][f];
        q = qred[0][f] + qred[1][f] + qred[2][f] + qred[3][f];
        int L = 127 - conv;
        float n = 128.f * (float)L;
        float mu = s / n;
        float var = fmaxf(q / n - mu * mu, 0.f);
        const float* gp = (conv == 0) ? g0 : (conv == 1) ? g1 : g2;
        const float* bp = (conv == 0) ? b0 : (conv == 1) ? b1 : b2;
        float a = gp[f] * rsqrtf(var + 1e-5f);
        af[conv * 256 + f] = a;
        df[conv * 256 + f] = bp[f] - mu * a;
    }
}

// ---------------- 4. pool + FC1: 128 blocks x 1024 threads ------------------
__global__ void pool_fc1(const float* __restrict__ mxF, const float* __restrict__ mnF,
                         const float* __restrict__ af, const float* __restrict__ df,
                         const float* __restrict__ fc1w, const float* __restrict__ fc1b,
                         float* __restrict__ zb) {
    int b = blockIdx.x;      // 0..127
    int tid = threadIdx.x;   // 0..1023
    __shared__ float pl[768];
    __shared__ float ps[8][100];
    if (tid < 768) {
        int conv = tid >> 8, f = tid & 255;
        size_t o = ((size_t)(conv * 128 + b)) * 256 + f;
        float a = af[tid], d = df[tid];
        float v = (a >= 0.f) ? mxF[o] : mnF[o];
        pl[tid] = fmaxf(a * v + d, 0.f);
    }
    __syncthreads();
    if (tid < 800) {
        int part = tid / 100, f = tid % 100;
        const float* pp = pl + part * 96;
        const float* wp = fc1w + (size_t)(part * 96) * 100 + f;
        float s = 0.f;
#pragma unroll 8
        for (int j = 0; j < 96; ++j) s += pp[j] * wp[(size_t)j * 100];
        ps[part][f] = s;
    }
    __syncthreads();
    if (tid < 100) {
        float s = fc1b[tid];
#pragma unroll
        for (int p = 0; p < 8; ++p) s += ps[p][tid];
        zb[b * 100 + tid] = s;
    }
}

// ---------------- 5. BN(batch) + relu + FC2 + softmax (1 block x 1024) ------
__global__ void fc2bn_kernel(const float* __restrict__ zb, const float* __restrict__ g1,
                             const float* __restrict__ b1, const float* __restrict__ fc2w,
                             const float* __restrict__ fc2b, float* __restrict__ out) {
    int tid = threadIdx.x;   // 0..1023
    __shared__ float z[128][101];
    __shared__ float av[100], dv[100];
    __shared__ float w2s[100][10];
    __shared__ float sst[8][100], qst[8][100];
    __shared__ float lgs[128][12];
    for (int i = tid; i < 12800; i += 1024) z[i / 100][i % 100] = zb[i];
    for (int i = tid; i < 1000; i += 1024) (&w2s[0][0])[i] = fc2w[i];
    __syncthreads();
    if (tid < 800) {
        int col = tid % 100, part = tid / 100;
        float s = 0.f, q = 0.f;
#pragma unroll 4
        for (int r = part * 16; r < part * 16 + 16; ++r) {
            float v = z[r][col]; s += v; q += v * v;
        }
        sst[part][col] = s; qst[part][col] = q;
    }
    __syncthreads();
    if (tid < 100) {
        float s = 0.f, q = 0.f;
#pragma unroll
        for (int p = 0; p < 8; ++p) { s += sst[p][tid]; q += qst[p][tid]; }
        float mu = s / 128.f;
        float var = fmaxf(q / 128.f - mu * mu, 0.f);
        float a = g1[tid] * rsqrtf(var + 1e-5f);
        av[tid] = a; dv[tid] = b1[tid] - mu * a;
    }
    __syncthreads();
    if (tid < 640) {
        int r = tid / 5, cg = tid % 5;
        int c0 = 2 * cg, c1 = c0 + 1;
        float l0 = fc2b[c0], l1 = fc2b[c1];
        for (int j = 0; j < 100; ++j) {
            float v = fmaxf(av[j] * z[r][j] + dv[j], 0.f);
            l0 += v * w2s[j][c0]; l1 += v * w2s[j][c1];
        }
        lgs[r][c0] = l0; lgs[r][c1] = l1;
    }
    __syncthreads();
    if (tid < 128) {
        int r = tid;
        float m = lgs[r][0];
#pragma unroll
        for (int c = 1; c < 10; ++c) m = fmaxf(m, lgs[r][c]);
        float e[10], sum = 0.f;
#pragma unroll
        for (int c = 0; c < 10; ++c) { e[c] = expf(lgs[r][c] - m); sum += e[c]; }
#pragma unroll
        for (int c = 0; c < 10; ++c) out[r * 10 + c] = e[c] / sum;
    }
}

// ---------------- launch -----------------------------------------------------
extern "C" void kernel_launch(void* const* d_in, const int* in_sizes, int n_in,
                              void* d_out, int out_size, void* d_ws, size_t ws_size,
                              hipStream_t stream) {
    const float* x    = (const float*)d_in[0];
    const float* embw = (const float*)d_in[1];
    const float* cw0 = (const float*)d_in[2],  *cb0 = (const float*)d_in[3];
    const float* bg0 = (const float*)d_in[4],  *bb0 = (const float*)d_in[5];
    const float* cw1 = (const float*)d_in[6],  *cb1 = (const float*)d_in[7];
    const float* bg1 = (const float*)d_in[8],  *bb1 = (const float*)d_in[9];
    const float* cw2 = (const float*)d_in[10], *cb2 = (const float*)d_in[11];
    const float* bg2 = (const float*)d_in[12], *bb2 = (const float*)d_in[13];
    const float* fc1w = (const float*)d_in[14], *fc1b = (const float*)d_in[15];
    const float* g1   = (const float*)d_in[16], *b1   = (const float*)d_in[17];
    const float* fc2w = (const float*)d_in[18], *fc2b = (const float*)d_in[19];

    char* ws = (char*)d_ws;
    short* emb  = (short*)(ws);
    short* Wtb  = (short*)(ws + 16781312);
    float* sumP = (float*)(ws + 19140608);
    float* ssqP = (float*)(ws + 19533824);
    float* mxF  = (float*)(ws + 19927040);
    float* mnF  = (float*)(ws + 20320256);
    float* af   = (float*)(ws + 20713472);
    float* df   = (float*)(ws + 20716544);
    float* zb   = (float*)(ws + 20719616);

    // MEASUREMENT: embed x4, conv x3, tail x1.
    embed_prep<<<PREPB + MPAD, 256, 0, stream>>>(x, embw, emb, cw0, cw1, cw2, Wtb, 4);
    conv_gemm<<<768, 256, 0, stream>>>(emb, Wtb, cb0, cb1, cb2,
                                       sumP, ssqP, mxF, mnF, 3);
    bn_stats<<<3, 1024, 0, stream>>>(sumP, ssqP, bg0, bg1, bg2, bb0, bb1, bb2, af, df);
    pool_fc1<<<128, 1024, 0, stream>>>(mxF, mnF, af, df, fc1w, fc1b, zb);
    fc2bn_kernel<<<1, 1024, 0, stream>>>(zb, g1, b1, fc2w, fc2b, (float*)d_out);
}

// Round 13
// 94.425 us; speedup vs baseline: 2.4039x; 2.4039x over previous
//
#include <hip/hip_runtime.h>
#include <cstdint>
#include <cstddef>

#define MTOT 16384      // B*S
#define MPAD 16388      // + 4 zero pad rows
#define INCH 512        // W*E
#define NF   256        // filters per conv
#define PREPB 6144      // prep blocks (2048 per conv)

typedef __attribute__((ext_vector_type(4))) float f32x4;
typedef __attribute__((ext_vector_type(8))) short bf16x8;

__device__ __forceinline__ short f2bf(float f) {
    union { float f; unsigned u; } v; v.f = f;
    unsigned r = v.u + 0x7FFFu + ((v.u >> 16) & 1u);
    return (short)(r >> 16);
}

__device__ __forceinline__ void gld16(const short* g, short* l) {
    __builtin_amdgcn_global_load_lds(
        (const __attribute__((address_space(1))) unsigned int*)g,
        (__attribute__((address_space(3))) unsigned int*)l,
        16, 0, 0);
}

// ---------------- 1. fused: conv-weight prep + embedding gather -------------
__global__ void embed_prep(const float* __restrict__ x, const float* __restrict__ ew,
                           short* __restrict__ emb,
                           const float* __restrict__ w0, const float* __restrict__ w1,
                           const float* __restrict__ w2, short* __restrict__ Wtb) {
    int tid = threadIdx.x;
    if (blockIdx.x < PREPB) {
        int blk = blockIdx.x;
        int conv = blk >> 11;
        int ki = conv + 2;
        int K = 512 * ki;
        int idx = (blk & 2047) * 256 + tid;
        if (idx >= K * NF) return;
        int u = idx >> 9;
        int ic = idx & 511;
        int f = u / ki;
        int j = u - f * ki;
        const float* w = (conv == 0) ? w0 : (conv == 1) ? w1 : w2;
        float val = w[(size_t)f * K + ic * ki + j];
        int k = j * 512 + ic;
        int kt = k >> 6, kl = k & 63;
        int kc = kl >> 3, klo = kl & 7;
        int nb = f >> 7, fr = f & 127;
        int cc = kc ^ (fr & 7);
        size_t off = (conv == 0) ? 0 : (conv == 1) ? 262144 : 655360;
        Wtb[off + (((size_t)(kt * 2 + nb) * 128 + fr) * 8 + cc) * 8 + klo] = f2bf(val);
        return;
    }
    int m = blockIdx.x - PREPB;
    if (m >= MTOT) {
        if (tid < 64) {
            uint4 z = make_uint4(0u, 0u, 0u, 0u);
            *(uint4*)&emb[(size_t)m * INCH + tid * 8] = z;
        }
        return;
    }
    int w = tid >> 4, u = tid & 15;
    const float* xr = x + ((size_t)m * 16 + w) * 128 + u * 8;
    float4 a0 = *(const float4*)xr;
    float4 a1 = *(const float4*)(xr + 4);
    float vals[8] = {a0.x, a0.y, a0.z, a0.w, a1.x, a1.y, a1.z, a1.w};
    int myidx = 0;
#pragma unroll
    for (int jj = 0; jj < 8; ++jj)
        if (vals[jj] != 0.f) myidx = u * 8 + jj;
#pragma unroll
    for (int off = 1; off < 16; off <<= 1)
        myidx = max(myidx, __shfl_xor(myidx, off));
    if (u < 4) {
        const float* er = ew + (size_t)myidx * 32 + u * 8;
        float4 e0 = *(const float4*)er;
        float4 e1 = *(const float4*)(er + 4);
        short h[8];
        h[0] = f2bf(e0.x); h[1] = f2bf(e0.y); h[2] = f2bf(e0.z); h[3] = f2bf(e0.w);
        h[4] = f2bf(e1.x); h[5] = f2bf(e1.y); h[6] = f2bf(e1.z); h[7] = f2bf(e1.w);
        *(uint4*)&emb[(size_t)m * INCH + w * 32 + u * 8] = *(uint4*)h;
    }
}

// ---------------- 2. conv GEMM: 128x128 tile, BK=64, 8 waves/block ----------
// Same 2-barrier skeleton as R11 (measured best); 512 threads so each SIMD
// hosts 6 waves (3 blocks x 8 waves / 4 SIMDs) -> stall coverage.
__launch_bounds__(512)
__global__ void conv_gemm(const short* __restrict__ emb, const short* __restrict__ Wtb,
                          const float* __restrict__ cb0, const float* __restrict__ cb1,
                          const float* __restrict__ cb2,
                          float* __restrict__ sumP, float* __restrict__ ssqP,
                          float* __restrict__ mxF, float* __restrict__ mnF) {
    int o = blockIdx.x;
    int logical = (o & 7) * 96 + (o >> 3);
    int mb = logical / 6;
    int r6 = logical - mb * 6;
    int conv = r6 >> 1;
    int nb = r6 & 1;
    int ki = conv + 2;
    int m0 = mb * 128;
    const short* Wc = Wtb + ((conv == 0) ? 0 : (conv == 1) ? 262144 : 655360);

    __shared__ __align__(16) short As[128 * 64];   // 16 KB
    __shared__ __align__(16) short Bs[128 * 64];   // 16 KB

    int tid = threadIdx.x;
    int wv = tid >> 6, lane = tid & 63, g = lane >> 4, ln = lane & 15;
    int wr = wv >> 2, wc = wv & 3;     // 2 x 4 wave grid; per-wave 64x32 out

    f32x4 acc[4][2];
#pragma unroll
    for (int i = 0; i < 4; ++i)
#pragma unroll
        for (int n = 0; n < 2; ++n) acc[i][n] = (f32x4){0.f, 0.f, 0.f, 0.f};

    // staging: 1024 chunks of 16B per tile; thread q-chunks = q*512 + tid
    int arow[2], acol[2];
#pragma unroll
    for (int q = 0; q < 2; ++q) {
        int c = q * 512 + tid;
        arow[q] = c >> 3;
        acol[q] = ((c & 7) ^ (arow[q] & 7)) * 8;   // pre-swizzled source col
    }

    // fragment read offsets (undo swizzle): data chunk d = kk*4+g at slot d^(row&7)
    int aOff[2][4], bOff[2][2];
#pragma unroll
    for (int kk = 0; kk < 2; ++kk) {
#pragma unroll
        for (int i = 0; i < 4; ++i) {
            int R = wr * 64 + i * 16 + ln;
            aOff[kk][i] = R * 64 + (((kk * 4 + g) ^ (R & 7)) * 8);
        }
#pragma unroll
        for (int i = 0; i < 2; ++i) {
            int F = wc * 32 + i * 16 + ln;
            bOff[kk][i] = F * 64 + (((kk * 4 + g) ^ (F & 7)) * 8);
        }
    }

    for (int j = 0; j < ki; ++j) {
        const short* embj = emb + (size_t)(m0 + j) * INCH;
        for (int ic0 = 0; ic0 < INCH; ic0 += 64) {
            int kt = j * 8 + (ic0 >> 6);
            const short* Bsrc = Wc + (size_t)(kt * 2 + nb) * 8192;
            __syncthreads();
#pragma unroll
            for (int q = 0; q < 2; ++q) {
                gld16(embj + (size_t)arow[q] * INCH + ic0 + acol[q],
                      As + q * 4096 + wv * 512);
                gld16(Bsrc + (q * 512 + tid) * 8,
                      Bs + q * 4096 + wv * 512);
            }
            __syncthreads();
#pragma unroll
            for (int kk = 0; kk < 2; ++kk) {
                bf16x8 afr[4], bfr[2];
#pragma unroll
                for (int mi = 0; mi < 4; ++mi) afr[mi] = *(const bf16x8*)&As[aOff[kk][mi]];
#pragma unroll
                for (int ni = 0; ni < 2; ++ni) bfr[ni] = *(const bf16x8*)&Bs[bOff[kk][ni]];
#pragma unroll
                for (int mi = 0; mi < 4; ++mi)
#pragma unroll
                    for (int ni = 0; ni < 2; ++ni)
                        acc[mi][ni] = __builtin_amdgcn_mfma_f32_16x16x32_bf16(afr[mi], bfr[ni], acc[mi][ni], 0, 0, 0);
            }
        }
    }

    // epilogue: bias + per-(b,f) {sum, sumsq, max, min}; block row = batch b
    int L = 127 - conv;
    const float* cbp = (conv == 0) ? cb0 : (conv == 1) ? cb1 : cb2;
    float s[2] = {0.f, 0.f}, q[2] = {0.f, 0.f};
    float mx[2], mn[2], cb[2];
#pragma unroll
    for (int ni = 0; ni < 2; ++ni) {
        mx[ni] = -3.0e38f; mn[ni] = 3.0e38f;
        cb[ni] = cbp[nb * 128 + wc * 32 + ni * 16 + ln];
    }
#pragma unroll
    for (int mi = 0; mi < 4; ++mi) {
#pragma unroll
        for (int r = 0; r < 4; ++r) {
            int t = wr * 64 + mi * 16 + g * 4 + r;   // t within batch row
            if (t >= L) continue;
#pragma unroll
            for (int ni = 0; ni < 2; ++ni) {
                float c = acc[mi][ni][r] + cb[ni];
                s[ni] += c; q[ni] += c * c;
                mx[ni] = fmaxf(mx[ni], c); mn[ni] = fminf(mn[ni], c);
            }
        }
    }
#pragma unroll
    for (int off = 16; off < 64; off <<= 1) {
#pragma unroll
        for (int ni = 0; ni < 2; ++ni) {
            s[ni] += __shfl_xor(s[ni], off);
            q[ni] += __shfl_xor(q[ni], off);
            mx[ni] = fmaxf(mx[ni], __shfl_xor(mx[ni], off));
            mn[ni] = fminf(mn[ni], __shfl_xor(mn[ni], off));
        }
    }
    __syncthreads();                    // done reading As; reuse as scratch
    float* sm = (float*)As;             // [4 stats][2 wr][128 col] = 4KB
    if (g == 0) {
#pragma unroll
        for (int ni = 0; ni < 2; ++ni) {
            int col = wc * 32 + ni * 16 + ln;
            int oo = wr * 128 + col;
            sm[oo] = s[ni]; sm[256 + oo] = q[ni];
            sm[512 + oo] = mx[ni]; sm[768 + oo] = mn[ni];
        }
    }
    __syncthreads();
    if (tid < 128) {
        float S  = sm[tid] + sm[128 + tid];
        float Q  = sm[256 + tid] + sm[384 + tid];
        float MX = fmaxf(sm[512 + tid], sm[640 + tid]);
        float MN = fminf(sm[768 + tid], sm[896 + tid]);
        size_t off2 = ((size_t)(conv * 128 + mb)) * 256 + nb * 128 + tid;   // coalesced
        sumP[off2] = S; ssqP[off2] = Q; mxF[off2] = MX; mnF[off2] = MN;
    }
}

// ---------------- 3. BN stats only: af/df[768] (3 blocks x 1024) ------------
__global__ void bn_stats(const float* __restrict__ sumP, const float* __restrict__ ssqP,
                         const float* __restrict__ g0, const float* __restrict__ g1,
                         const float* __restrict__ g2,
                         const float* __restrict__ b0, const float* __restrict__ b1,
                         const float* __restrict__ b2,
                         float* __restrict__ af, float* __restrict__ df) {
    int conv = blockIdx.x;
    int tid = threadIdx.x;
    int part = tid >> 8, f = tid & 255;
    float s = 0.f, q = 0.f;
#pragma unroll 4
    for (int mb = part * 32; mb < part * 32 + 32; ++mb) {
        size_t o = ((size_t)(conv * 128 + mb)) * 256 + f;
        s += sumP[o]; q += ssqP[o];
    }
    __shared__ float sred[4][256], qred[4][256];
    sred[part][f] = s; qred[part][f] = q;
    __syncthreads();
    if (part == 0) {
        s = sred[0][f] + sred[1][f] + sred[2][f] + sred[3][f];
        q = qred[0][f] + qred[1][f] + qred[2][f] + qred[3][f];
        int L = 127 - conv;
        float n = 128.f * (float)L;
        float mu = s / n;
        float var = fmaxf(q / n - mu * mu, 0.f);
        const float* gp = (conv == 0) ? g0 : (conv == 1) ? g1 : g2;
        const float* bp = (conv == 0) ? b0 : (conv == 1) ? b1 : b2;
        float a = gp[f] * rsqrtf(var + 1e-5f);
        af[conv * 256 + f] = a;
        df[conv * 256 + f] = bp[f] - mu * a;
    }
}

// ---------------- 4. pool + FC1: 128 blocks x 1024 threads ------------------
__global__ void pool_fc1(const float* __restrict__ mxF, const float* __restrict__ mnF,
                         const float* __restrict__ af, const float* __restrict__ df,
                         const float* __restrict__ fc1w, const float* __restrict__ fc1b,
                         float* __restrict__ zb) {
    int b = blockIdx.x;      // 0..127
    int tid = threadIdx.x;   // 0..1023
    __shared__ float pl[768];
    __shared__ float ps[8][100];
    if (tid < 768) {
        int conv = tid >> 8, f = tid & 255;
        size_t o = ((size_t)(conv * 128 + b)) * 256 + f;
        float a = af[tid], d = df[tid];
        float v = (a >= 0.f) ? mxF[o] : mnF[o];
        pl[tid] = fmaxf(a * v + d, 0.f);
    }
    __syncthreads();
    if (tid < 800) {
        int part = tid / 100, f = tid % 100;
        const float* pp = pl + part * 96;
        const float* wp = fc1w + (size_t)(part * 96) * 100 + f;
        float s = 0.f;
#pragma unroll 8
        for (int j = 0; j < 96; ++j) s += pp[j] * wp[(size_t)j * 100];
        ps[part][f] = s;
    }
    __syncthreads();
    if (tid < 100) {
        float s = fc1b[tid];
#pragma unroll
        for (int p = 0; p < 8; ++p) s += ps[p][tid];
        zb[b * 100 + tid] = s;
    }
}

// ---------------- 5. BN(batch) + relu + FC2 + softmax (1 block x 1024) ------
__global__ void fc2bn_kernel(const float* __restrict__ zb, const float* __restrict__ g1,
                             const float* __restrict__ b1, const float* __restrict__ fc2w,
                             const float* __restrict__ fc2b, float* __restrict__ out) {
    int tid = threadIdx.x;   // 0..1023
    __shared__ float z[128][101];
    __shared__ float av[100], dv[100];
    __shared__ float w2s[100][10];
    __shared__ float sst[8][100], qst[8][100];
    __shared__ float lgs[128][12];
    for (int i = tid; i < 12800; i += 1024) z[i / 100][i % 100] = zb[i];
    for (int i = tid; i < 1000; i += 1024) (&w2s[0][0])[i] = fc2w[i];
    __syncthreads();
    if (tid < 800) {
        int col = tid % 100, part = tid / 100;
        float s = 0.f, q = 0.f;
#pragma unroll 4
        for (int r = part * 16; r < part * 16 + 16; ++r) {
            float v = z[r][col]; s += v; q += v * v;
        }
        sst[part][col] = s; qst[part][col] = q;
    }
    __syncthreads();
    if (tid < 100) {
        float s = 0.f, q = 0.f;
#pragma unroll
        for (int p = 0; p < 8; ++p) { s += sst[p][tid]; q += qst[p][tid]; }
        float mu = s / 128.f;
        float var = fmaxf(q / 128.f - mu * mu, 0.f);
        float a = g1[tid] * rsqrtf(var + 1e-5f);
        av[tid] = a; dv[tid] = b1[tid] - mu * a;
    }
    __syncthreads();
    if (tid < 640) {
        int r = tid / 5, cg = tid % 5;
        int c0 = 2 * cg, c1 = c0 + 1;
        float l0 = fc2b[c0], l1 = fc2b[c1];
        for (int j = 0; j < 100; ++j) {
            float v = fmaxf(av[j] * z[r][j] + dv[j], 0.f);
            l0 += v * w2s[j][c0]; l1 += v * w2s[j][c1];
        }
        lgs[r][c0] = l0; lgs[r][c1] = l1;
    }
    __syncthreads();
    if (tid < 128) {
        int r = tid;
        float m = lgs[r][0];
#pragma unroll
        for (int c = 1; c < 10; ++c) m = fmaxf(m, lgs[r][c]);
        float e[10], sum = 0.f;
#pragma unroll
        for (int c = 0; c < 10; ++c) { e[c] = expf(lgs[r][c] - m); sum += e[c]; }
#pragma unroll
        for (int c = 0; c < 10; ++c) out[r * 10 + c] = e[c] / sum;
    }
}

// ---------------- launch -----------------------------------------------------
extern "C" void kernel_launch(void* const* d_in, const int* in_sizes, int n_in,
                              void* d_out, int out_size, void* d_ws, size_t ws_size,
                              hipStream_t stream) {
    const float* x    = (const float*)d_in[0];
    const float* embw = (const float*)d_in[1];
    const float* cw0 = (const float*)d_in[2],  *cb0 = (const float*)d_in[3];
    const float* bg0 = (const float*)d_in[4],  *bb0 = (const float*)d_in[5];
    const float* cw1 = (const float*)d_in[6],  *cb1 = (const float*)d_in[7];
    const float* bg1 = (const float*)d_in[8],  *bb1 = (const float*)d_in[9];
    const float* cw2 = (const float*)d_in[10], *cb2 = (const float*)d_in[11];
    const float* bg2 = (const float*)d_in[12], *bb2 = (const float*)d_in[13];
    const float* fc1w = (const float*)d_in[14], *fc1b = (const float*)d_in[15];
    const float* g1   = (const float*)d_in[16], *b1   = (const float*)d_in[17];
    const float* fc2w = (const float*)d_in[18], *fc2b = (const float*)d_in[19];

    char* ws = (char*)d_ws;
    short* emb  = (short*)(ws);
    short* Wtb  = (short*)(ws + 16781312);
    float* sumP = (float*)(ws + 19140608);
    float* ssqP = (float*)(ws + 19533824);
    float* mxF  = (float*)(ws + 19927040);
    float* mnF  = (float*)(ws + 20320256);
    float* af   = (float*)(ws + 20713472);
    float* df   = (float*)(ws + 20716544);
    float* zb   = (float*)(ws + 20719616);

    embed_prep<<<PREPB + MPAD, 256, 0, stream>>>(x, embw, emb, cw0, cw1, cw2, Wtb);
    conv_gemm<<<768, 512, 0, stream>>>(emb, Wtb, cb0, cb1, cb2,
                                       sumP, ssqP, mxF, mnF);
    bn_stats<<<3, 1024, 0, stream>>>(sumP, ssqP, bg0, bg1, bg2, bb0, bb1, bb2, af, df);
    pool_fc1<<<128, 1024, 0, stream>>>(mxF, mnF, af, df, fc1w, fc1b, zb);
    fc2bn_kernel<<<1, 1024, 0, stream>>>(zb, g1, b1, fc2w, fc2b, (float*)d_out);
}

// Round 14
// 92.609 us; speedup vs baseline: 2.4511x; 1.0196x over previous
//
#include <hip/hip_runtime.h>
#include <cstdint>
#include <cstddef>

#define MTOT 16384      // B*S
#define MPAD 16388      // + 4 zero pad rows
#define INCH 512        // W*E
#define NF   256        // filters per conv
#define PREPB 6144      // prep blocks (2048 per conv)

typedef __attribute__((ext_vector_type(4))) float f32x4;
typedef __attribute__((ext_vector_type(8))) short bf16x8;

__device__ __forceinline__ short f2bf(float f) {
    union { float f; unsigned u; } v; v.f = f;
    unsigned r = v.u + 0x7FFFu + ((v.u >> 16) & 1u);
    return (short)(r >> 16);
}

__device__ __forceinline__ void gld16(const short* g, short* l) {
    __builtin_amdgcn_global_load_lds(
        (const __attribute__((address_space(1))) unsigned int*)g,
        (__attribute__((address_space(3))) unsigned int*)l,
        16, 0, 0);
}

// ---------------- 1. fused: conv-weight prep + embedding gather -------------
// Weight layout (BK=32): [kt(k>>5)][nb][128 fr][4 cc][8 klo], cc = kc^((fr>>1)&3)
__global__ void embed_prep(const float* __restrict__ x, const float* __restrict__ ew,
                           short* __restrict__ emb,
                           const float* __restrict__ w0, const float* __restrict__ w1,
                           const float* __restrict__ w2, short* __restrict__ Wtb) {
    int tid = threadIdx.x;
    if (blockIdx.x < PREPB) {
        int blk = blockIdx.x;
        int conv = blk >> 11;
        int ki = conv + 2;
        int K = 512 * ki;
        int idx = (blk & 2047) * 256 + tid;
        if (idx >= K * NF) return;
        int u = idx >> 9;
        int ic = idx & 511;
        int f = u / ki;
        int j = u - f * ki;
        const float* w = (conv == 0) ? w0 : (conv == 1) ? w1 : w2;
        float val = w[(size_t)f * K + ic * ki + j];
        int k = j * 512 + ic;
        int kt = k >> 5, kl = k & 31;
        int kc = kl >> 3, klo = kl & 7;
        int nb = f >> 7, fr = f & 127;
        int cc = kc ^ ((fr >> 1) & 3);
        size_t off = (conv == 0) ? 0 : (conv == 1) ? 262144 : 655360;
        Wtb[off + (((size_t)(kt * 2 + nb) * 128 + fr) * 4 + cc) * 8 + klo] = f2bf(val);
        return;
    }
    int m = blockIdx.x - PREPB;
    if (m >= MTOT) {
        if (tid < 64) {
            uint4 z = make_uint4(0u, 0u, 0u, 0u);
            *(uint4*)&emb[(size_t)m * INCH + tid * 8] = z;
        }
        return;
    }
    int w = tid >> 4, u = tid & 15;
    const float* xr = x + ((size_t)m * 16 + w) * 128 + u * 8;
    float4 a0 = *(const float4*)xr;
    float4 a1 = *(const float4*)(xr + 4);
    float vals[8] = {a0.x, a0.y, a0.z, a0.w, a1.x, a1.y, a1.z, a1.w};
    int myidx = 0;
#pragma unroll
    for (int jj = 0; jj < 8; ++jj)
        if (vals[jj] != 0.f) myidx = u * 8 + jj;
#pragma unroll
    for (int off = 1; off < 16; off <<= 1)
        myidx = max(myidx, __shfl_xor(myidx, off));
    if (u < 4) {
        const float* er = ew + (size_t)myidx * 32 + u * 8;
        float4 e0 = *(const float4*)er;
        float4 e1 = *(const float4*)(er + 4);
        short h[8];
        h[0] = f2bf(e0.x); h[1] = f2bf(e0.y); h[2] = f2bf(e0.z); h[3] = f2bf(e0.w);
        h[4] = f2bf(e1.x); h[5] = f2bf(e1.y); h[6] = f2bf(e1.z); h[7] = f2bf(e1.w);
        *(uint4*)&emb[(size_t)m * INCH + w * 32 + u * 8] = *(uint4*)h;
    }
}

// ---------------- 2. conv GEMM: BK=32, A staged once, j-shift in LDS reads --
// Per ic-step: stage A rows m0..m0+131 ONCE + ki B slices -> ONE drain per
// ki*16 MFMAs/wave. Barriers per block: 32 (vs 16*ki before).
__launch_bounds__(256)
__global__ void conv_gemm(const short* __restrict__ emb, const short* __restrict__ Wtb,
                          const float* __restrict__ cb0, const float* __restrict__ cb1,
                          const float* __restrict__ cb2,
                          float* __restrict__ sumP, float* __restrict__ ssqP,
                          float* __restrict__ mxF, float* __restrict__ mnF) {
    int o = blockIdx.x;
    int logical = (o & 7) * 96 + (o >> 3);
    int mb = logical / 6;
    int r6 = logical - mb * 6;
    int conv = r6 >> 1;
    int nb = r6 & 1;
    int ki = conv + 2;
    int m0 = mb * 128;
    const short* Wc = Wtb + ((conv == 0) ? 0 : (conv == 1) ? 262144 : 655360);

    __shared__ __align__(16) short As[132 * 32];    // 8.25 KB (132 rows)
    __shared__ __align__(16) short Bs[4 * 4096];    // 32 KB (4 j-slices)

    int tid = threadIdx.x;
    int wv = tid >> 6, lane = tid & 63, g = lane >> 4, ln = lane & 15;
    int wr = wv >> 1, wc = wv & 1;

    f32x4 acc[4][4];
#pragma unroll
    for (int i = 0; i < 4; ++i)
#pragma unroll
        for (int n = 0; n < 4; ++n) acc[i][n] = (f32x4){0.f, 0.f, 0.f, 0.f};

    // A staging: 528 chunks (132 rows x 4); thread chunks tid, 256+tid;
    // chunks 512..527 (rows 128..131) via explicit load+ds_write (tid<16).
    int arow0 = tid >> 2, acol0 = (((tid)&3) ^ ((arow0 >> 1) & 3)) * 8;
    int arow1 = (256 + tid) >> 2, acol1 = (((256 + tid) & 3) ^ ((arow1 >> 1) & 3)) * 8;
    int xrow = 128 + (tid >> 2);
    int xcol = (((tid) & 3) ^ ((xrow >> 1) & 3)) * 8;
    int c0 = tid, c1 = 256 + tid;

    // B fragment offsets (per j-buffer base added in loop)
    int bOff[4];
#pragma unroll
    for (int i = 0; i < 4; ++i) {
        int F = wc * 64 + i * 16 + ln;
        bOff[i] = F * 32 + ((g ^ ((F >> 1) & 3)) * 8);
    }
    int Rb[4];
#pragma unroll
    for (int i = 0; i < 4; ++i) Rb[i] = wr * 64 + i * 16 + ln;

    for (int ic0 = 0; ic0 < INCH; ic0 += 32) {
        int kt0 = ic0 >> 5;
        const short* abase = emb + (size_t)m0 * INCH + ic0;
        __syncthreads();                      // prior compute done: buffers free
        gld16(abase + (size_t)arow0 * INCH + acol0, As + wv * 512);
        gld16(abase + (size_t)arow1 * INCH + acol1, As + 2048 + wv * 512);
        if (tid < 16) {                       // boundary rows 128..131
            bf16x8 v = *(const bf16x8*)&abase[(size_t)xrow * INCH + xcol];
            *(bf16x8*)&As[(512 + tid) * 8] = v;
        }
        for (int jj = 0; jj < ki; ++jj) {
            const short* Bsrc = Wc + (size_t)((jj * 16 + kt0) * 2 + nb) * 4096;
            gld16(Bsrc + c0 * 8, Bs + jj * 4096 + wv * 512);
            gld16(Bsrc + c1 * 8, Bs + jj * 4096 + 2048 + wv * 512);
        }
        __syncthreads();                      // staged data visible
        for (int jj = 0; jj < ki; ++jj) {
            bf16x8 afr[4], bfr[4];
#pragma unroll
            for (int i = 0; i < 4; ++i) {
                int Rj = Rb[i] + jj;
                afr[i] = *(const bf16x8*)&As[Rj * 32 + ((g ^ ((Rj >> 1) & 3)) * 8)];
            }
#pragma unroll
            for (int i = 0; i < 4; ++i) bfr[i] = *(const bf16x8*)&Bs[jj * 4096 + bOff[i]];
#pragma unroll
            for (int mi = 0; mi < 4; ++mi)
#pragma unroll
                for (int ni = 0; ni < 4; ++ni)
                    acc[mi][ni] = __builtin_amdgcn_mfma_f32_16x16x32_bf16(afr[mi], bfr[ni], acc[mi][ni], 0, 0, 0);
        }
    }

    // epilogue: bias + per-(b,f) {sum, sumsq, max, min}; block row = batch b
    int L = 127 - conv;
    const float* cbp = (conv == 0) ? cb0 : (conv == 1) ? cb1 : cb2;
    float s[4] = {0.f, 0.f, 0.f, 0.f}, q[4] = {0.f, 0.f, 0.f, 0.f};
    float mx[4], mn[4], cb[4];
#pragma unroll
    for (int ni = 0; ni < 4; ++ni) {
        mx[ni] = -3.0e38f; mn[ni] = 3.0e38f;
        cb[ni] = cbp[nb * 128 + wc * 64 + ni * 16 + ln];
    }
#pragma unroll
    for (int mi = 0; mi < 4; ++mi) {
#pragma unroll
        for (int r = 0; r < 4; ++r) {
            int t = wr * 64 + mi * 16 + g * 4 + r;
            if (t >= L) continue;
#pragma unroll
            for (int ni = 0; ni < 4; ++ni) {
                float c = acc[mi][ni][r] + cb[ni];
                s[ni] += c; q[ni] += c * c;
                mx[ni] = fmaxf(mx[ni], c); mn[ni] = fminf(mn[ni], c);
            }
        }
    }
#pragma unroll
    for (int off = 16; off < 64; off <<= 1) {
#pragma unroll
        for (int ni = 0; ni < 4; ++ni) {
            s[ni] += __shfl_xor(s[ni], off);
            q[ni] += __shfl_xor(q[ni], off);
            mx[ni] = fmaxf(mx[ni], __shfl_xor(mx[ni], off));
            mn[ni] = fminf(mn[ni], __shfl_xor(mn[ni], off));
        }
    }
    __syncthreads();
    float* sm = (float*)As;
    if (g == 0) {
#pragma unroll
        for (int ni = 0; ni < 4; ++ni) {
            int col = wc * 64 + ni * 16 + ln;
            int oo = wr * 128 + col;
            sm[oo] = s[ni]; sm[256 + oo] = q[ni];
            sm[512 + oo] = mx[ni]; sm[768 + oo] = mn[ni];
        }
    }
    __syncthreads();
    if (tid < 128) {
        float S  = sm[tid] + sm[128 + tid];
        float Q  = sm[256 + tid] + sm[384 + tid];
        float MX = fmaxf(sm[512 + tid], sm[640 + tid]);
        float MN = fminf(sm[768 + tid], sm[896 + tid]);
        size_t off2 = ((size_t)(conv * 128 + mb)) * 256 + nb * 128 + tid;
        sumP[off2] = S; ssqP[off2] = Q; mxF[off2] = MX; mnF[off2] = MN;
    }
}

// ---------------- 3. BN stats only: af/df[768] (3 blocks x 1024) ------------
__global__ void bn_stats(const float* __restrict__ sumP, const float* __restrict__ ssqP,
                         const float* __restrict__ g0, const float* __restrict__ g1,
                         const float* __restrict__ g2,
                         const float* __restrict__ b0, const float* __restrict__ b1,
                         const float* __restrict__ b2,
                         float* __restrict__ af, float* __restrict__ df) {
    int conv = blockIdx.x;
    int tid = threadIdx.x;
    int part = tid >> 8, f = tid & 255;
    float s = 0.f, q = 0.f;
#pragma unroll 4
    for (int mb = part * 32; mb < part * 32 + 32; ++mb) {
        size_t o = ((size_t)(conv * 128 + mb)) * 256 + f;
        s += sumP[o]; q += ssqP[o];
    }
    __shared__ float sred[4][256], qred[4][256];
    sred[part][f] = s; qred[part][f] = q;
    __syncthreads();
    if (part == 0) {
        s = sred[0][f] + sred[1][f] + sred[2][f] + sred[3][f];
        q = qred[0][f] + qred[1][f] + qred[2][f] + qred[3][f];
        int L = 127 - conv;
        float n = 128.f * (float)L;
        float mu = s / n;
        float var = fmaxf(q / n - mu * mu, 0.f);
        const float* gp = (conv == 0) ? g0 : (conv == 1) ? g1 : g2;
        const float* bp = (conv == 0) ? b0 : (conv == 1) ? b1 : b2;
        float a = gp[f] * rsqrtf(var + 1e-5f);
        af[conv * 256 + f] = a;
        df[conv * 256 + f] = bp[f] - mu * a;
    }
}

// ---------------- 4. pool + FC1: 128 blocks x 1024 threads ------------------
__global__ void pool_fc1(const float* __restrict__ mxF, const float* __restrict__ mnF,
                         const float* __restrict__ af, const float* __restrict__ df,
                         const float* __restrict__ fc1w, const float* __restrict__ fc1b,
                         float* __restrict__ zb) {
    int b = blockIdx.x;
    int tid = threadIdx.x;
    __shared__ float pl[768];
    __shared__ float ps[8][100];
    if (tid < 768) {
        int conv = tid >> 8, f = tid & 255;
        size_t o = ((size_t)(conv * 128 + b)) * 256 + f;
        float a = af[tid], d = df[tid];
        float v = (a >= 0.f) ? mxF[o] : mnF[o];
        pl[tid] = fmaxf(a * v + d, 0.f);
    }
    __syncthreads();
    if (tid < 800) {
        int part = tid / 100, f = tid % 100;
        const float* pp = pl + part * 96;
        const float* wp = fc1w + (size_t)(part * 96) * 100 + f;
        float s = 0.f;
#pragma unroll 8
        for (int j = 0; j < 96; ++j) s += pp[j] * wp[(size_t)j * 100];
        ps[part][f] = s;
    }
    __syncthreads();
    if (tid < 100) {
        float s = fc1b[tid];
#pragma unroll
        for (int p = 0; p < 8; ++p) s += ps[p][tid];
        zb[b * 100 + tid] = s;
    }
}

// ---------------- 5. BN(batch) + relu + FC2 + softmax (1 block x 1024) ------
__global__ void fc2bn_kernel(const float* __restrict__ zb, const float* __restrict__ g1,
                             const float* __restrict__ b1, const float* __restrict__ fc2w,
                             const float* __restrict__ fc2b, float* __restrict__ out) {
    int tid = threadIdx.x;
    __shared__ float z[128][101];
    __shared__ float av[100], dv[100];
    __shared__ float w2s[100][10];
    __shared__ float sst[8][100], qst[8][100];
    __shared__ float lgs[128][12];
    for (int i = tid; i < 12800; i += 1024) z[i / 100][i % 100] = zb[i];
    for (int i = tid; i < 1000; i += 1024) (&w2s[0][0])[i] = fc2w[i];
    __syncthreads();
    if (tid < 800) {
        int col = tid % 100, part = tid / 100;
        float s = 0.f, q = 0.f;
#pragma unroll 4
        for (int r = part * 16; r < part * 16 + 16; ++r) {
            float v = z[r][col]; s += v; q += v * v;
        }
        sst[part][col] = s; qst[part][col] = q;
    }
    __syncthreads();
    if (tid < 100) {
        float s = 0.f, q = 0.f;
#pragma unroll
        for (int p = 0; p < 8; ++p) { s += sst[p][tid]; q += qst[p][tid]; }
        float mu = s / 128.f;
        float var = fmaxf(q / 128.f - mu * mu, 0.f);
        float a = g1[tid] * rsqrtf(var + 1e-5f);
        av[tid] = a; dv[tid] = b1[tid] - mu * a;
    }
    __syncthreads();
    if (tid < 640) {
        int r = tid / 5, cg = tid % 5;
        int c0 = 2 * cg, c1 = c0 + 1;
        float l0 = fc2b[c0], l1 = fc2b[c1];
        for (int j = 0; j < 100; ++j) {
            float v = fmaxf(av[j] * z[r][j] + dv[j], 0.f);
            l0 += v * w2s[j][c0]; l1 += v * w2s[j][c1];
        }
        lgs[r][c0] = l0; lgs[r][c1] = l1;
    }
    __syncthreads();
    if (tid < 128) {
        int r = tid;
        float m = lgs[r][0];
#pragma unroll
        for (int c = 1; c < 10; ++c) m = fmaxf(m, lgs[r][c]);
        float e[10], sum = 0.f;
#pragma unroll
        for (int c = 0; c < 10; ++c) { e[c] = expf(lgs[r][c] - m); sum += e[c]; }
#pragma unroll
        for (int c = 0; c < 10; ++c) out[r * 10 + c] = e[c] / sum;
    }
}

// ---------------- launch -----------------------------------------------------
extern "C" void kernel_launch(void* const* d_in, const int* in_sizes, int n_in,
                              void* d_out, int out_size, void* d_ws, size_t ws_size,
                              hipStream_t stream) {
    const float* x    = (const float*)d_in[0];
    const float* embw = (const float*)d_in[1];
    const float* cw0 = (const float*)d_in[2],  *cb0 = (const float*)d_in[3];
    const float* bg0 = (const float*)d_in[4],  *bb0 = (const float*)d_in[5];
    const float* cw1 = (const float*)d_in[6],  *cb1 = (const float*)d_in[7];
    const float* bg1 = (const float*)d_in[8],  *bb1 = (const float*)d_in[9];
    const float* cw2 = (const float*)d_in[10], *cb2 = (const float*)d_in[11];
    const float* bg2 = (const float*)d_in[12], *bb2 = (const float*)d_in[13];
    const float* fc1w = (const float*)d_in[14], *fc1b = (const float*)d_in[15];
    const float* g1   = (const float*)d_in[16], *b1   = (const float*)d_in[17];
    const float* fc2w = (const float*)d_in[18], *fc2b = (const float*)d_in[19];

    char* ws = (char*)d_ws;
    short* emb  = (short*)(ws);
    short* Wtb  = (short*)(ws + 16781312);
    float* sumP = (float*)(ws + 19140608);
    float* ssqP = (float*)(ws + 19533824);
    float* mxF  = (float*)(ws + 19927040);
    float* mnF  = (float*)(ws + 20320256);
    float* af   = (float*)(ws + 20713472);
    float* df   = (float*)(ws + 20716544);
    float* zb   = (float*)(ws + 20719616);

    embed_prep<<<PREPB + MPAD, 256, 0, stream>>>(x, embw, emb, cw0, cw1, cw2, Wtb);
    conv_gemm<<<768, 256, 0, stream>>>(emb, Wtb, cb0, cb1, cb2,
                                       sumP, ssqP, mxF, mnF);
    bn_stats<<<3, 1024, 0, stream>>>(sumP, ssqP, bg0, bg1, bg2, bb0, bb1, bb2, af, df);
    pool_fc1<<<128, 1024, 0, stream>>>(mxF, mnF, af, df, fc1w, fc1b, zb);
    fc2bn_kernel<<<1, 1024, 0, stream>>>(zb, g1, b1, fc2w, fc2b, (float*)d_out);
}